// Round 4
// baseline (188.877 us; speedup 1.0000x reference)
//
#include <hip/hip_runtime.h>
#include <hip/hip_bf16.h>
#include <stdint.h>

// out[8192,4096] = x[8192,2048] @ WeffT^T ; WeffT built from W (4096,2048).
#define M_DIM 8192
#define K_DIM 2048
#define N_DIM 4096
#define BM 256
#define BN 256
#define BK 64
#define NT (K_DIM / BK)    // 32 K-tiles
#define NITER (NT / 2)     // 16 iterations, 2 K-tiles each

typedef __attribute__((ext_vector_type(8)))  short bf16x8;
typedef __attribute__((ext_vector_type(16))) float f32x16;

__device__ __forceinline__ unsigned short f2bfu(float f) {
    __hip_bfloat16 h = __float2bfloat16(f);
    return __builtin_bit_cast(unsigned short, h);
}

// ---------------------------------------------------------------------------
// Kernel 1: WeffT[o][i] (N x K row-major, bf16).
// v2: wo cached in LDS (7 shifted terms read from LDS), 6 coalesced global
// row streams, i = tid + 256*j so ushort stores are 128B-contiguous per wave.
// ---------------------------------------------------------------------------
__global__ __launch_bounds__(256) void build_weff(const float* __restrict__ W,
                                                  unsigned short* __restrict__ WT) {
    __shared__ float row[K_DIM];
    const int o = blockIdx.x;
    const float* wo = W + (size_t)o * K_DIM;
#pragma unroll
    for (int t = 0; t < 2; ++t)
        ((float4*)row)[threadIdx.x + 256 * t] = ((const float4*)wo)[threadIdx.x + 256 * t];
    __syncthreads();

    const float* rF = W + (size_t)(N_DIM - 1 - o) * K_DIM;
    const float* r1 = W + (size_t)((o - 1) & (N_DIM - 1)) * K_DIM;
    const float* r2 = W + (size_t)((o - 2) & (N_DIM - 1)) * K_DIM;
    const float* r3 = W + (size_t)((o - 3) & (N_DIM - 1)) * K_DIM;
    const float* r4 = W + (size_t)((o - 4) & (N_DIM - 1)) * K_DIM;
    const float* r5 = W + (size_t)((o - 5) & (N_DIM - 1)) * K_DIM;

    unsigned short* wt = WT + (size_t)o * K_DIM;
#pragma unroll
    for (int j = 0; j < 8; ++j) {
        const int i = threadIdx.x + 256 * j;
        float s = row[i] + row[K_DIM - 1 - i]
                + row[(i - 1) & (K_DIM - 1)] + row[(i - 2) & (K_DIM - 1)]
                + row[(i - 3) & (K_DIM - 1)] + row[(i - 4) & (K_DIM - 1)]
                + row[(i - 5) & (K_DIM - 1)];
        s += rF[i] + r1[i] + r2[i] + r3[i] + r4[i] + r5[i];
        wt[i] = f2bfu(s);
    }
}

// ---------------------------------------------------------------------------
// Kernel 2: x fp32 -> bf16
// ---------------------------------------------------------------------------
__global__ void cvt_x_kernel(const float* __restrict__ x, unsigned short* __restrict__ xb) {
    const int idx = blockIdx.x * 256 + threadIdx.x;
    float4 v = ((const float4*)x)[idx];
    ushort4 o;
    o.x = f2bfu(v.x); o.y = f2bfu(v.y); o.z = f2bfu(v.z); o.w = f2bfu(v.w);
    ((ushort4*)xb)[idx] = o;
}

// ---------------------------------------------------------------------------
// Kernel 3: 256x256 / BK=64 / 8 waves (2Mx4N) / 8-phase schedule, 32x32x16 MFMA.
//
// LDS per buffer p (64 KiB @ p*65536): A[256][64]bf16 @0 (A0 rows0-127 @0,
// A1 @16384), B @32768 (B0 @32768, B1 @49152). Row=128B=8x16B slots, physical
// slot = logical ^ (row&7) (both-sides swizzle, rule #21).
//
// Wave-tile 128x64 = 4 M-frags(32) x 2 N-frags(32); K-tile = 4 k-steps of 16.
// Phase Q: {4 a ds_reads (M-frag Q, ks=0..3) [+8 b reads ph1/5] | stage 1
// half-tile} -> barrier -> lgkmcnt(0) -> setprio(1) 8x mfma_32x32x16 setprio(0)
// -> [vmcnt(4) at ph4/ph8] -> barrier.  Identical sync skeleton to R3.
// ---------------------------------------------------------------------------
__global__ __launch_bounds__(512, 2) void gemm8p(const unsigned short* __restrict__ Ab,
                                                 const unsigned short* __restrict__ Bt,
                                                 float* __restrict__ C) {
    __shared__ __align__(16) char smem[2 * 65536];

    const int tid  = threadIdx.x;
    const int wave = tid >> 6;
    const int lane = tid & 63;

    // XCD-bijective swizzle (nwg = 512, % 8 == 0)
    const int nwg = gridDim.x;
    const int cpx = nwg >> 3;
    const int wg  = (blockIdx.x & 7) * cpx + (blockIdx.x >> 3);
    const int nbn = N_DIM / BN;                 // 16
    const int bm0 = (wg / nbn) * BM;
    const int bn0 = (wg % nbn) * BN;

    const int wr = wave >> 2;                   // 0..1 (M)
    const int wc = wave & 3;                    // 0..3 (N)

    // ---- staging (pre-swizzled global source) ----
    const int srow = tid >> 3;                          // row within 64-row chunk
    const int lsw  = (lane & 7) ^ ((lane >> 3) & 7);    // logical slot fetched
    const unsigned short* gA0 = Ab + (size_t)(bm0 + srow) * K_DIM + lsw * 8;
    const unsigned short* gB0 = Bt + (size_t)(bn0 + srow) * K_DIM + lsw * 8;

    // ---- ds_read addressing (32x32x16 fragments, swizzled) ----
    const int l31 = lane & 31;
    const int x7  = lane & 7;
    const int kh  = lane >> 5;                           // k-half select
    int sl[4];
#pragma unroll
    for (int ks = 0; ks < 4; ++ks) sl[ks] = ((kh + 2 * ks) ^ x7) * 16;  // phys slot byte
    const int aRow = (wr * 128 + l31) * 128;             // byte base, A region (add Q*4096)
    const int bR0  = (wc * 64 + l31) * 128 + 32768;      // nf=0
    const int bR1  = bR0 + 32 * 128;                     // nf=1

    f32x16 acc[8] = {};     // [mf*2 + nf]
    bf16x8 b[2][4];         // [nf][ks]

#define STAGE_HALF(gbase, opoff, h, t, p) do {                                              \
    char* lds_ = smem + (p) * 65536 + (opoff) + (h) * 16384 + wave * 1024;                  \
    const unsigned short* g_ = (gbase) + (size_t)((h) * 128) * K_DIM + (t) * BK;            \
    __builtin_amdgcn_global_load_lds(                                                        \
        (const __attribute__((address_space(1))) unsigned int*)g_,                           \
        (__attribute__((address_space(3))) unsigned int*)lds_, 16, 0, 0);                    \
    __builtin_amdgcn_global_load_lds(                                                        \
        (const __attribute__((address_space(1))) unsigned int*)(g_ + (size_t)64 * K_DIM),    \
        (__attribute__((address_space(3))) unsigned int*)(lds_ + 8192), 16, 0, 0);           \
} while (0)

#define PHASE(P, Q, LOADB, STAGE_STMT, VM_STMT) do {                                        \
    const char* base_ = smem + (P) * 65536;                                                 \
    bf16x8 a_[4];                                                                           \
    if (LOADB) {                                                                            \
        _Pragma("unroll")                                                                   \
        for (int ks = 0; ks < 4; ++ks) {                                                    \
            b[0][ks] = *(const bf16x8*)(base_ + bR0 + sl[ks]);                              \
            b[1][ks] = *(const bf16x8*)(base_ + bR1 + sl[ks]);                              \
        }                                                                                   \
    }                                                                                       \
    _Pragma("unroll")                                                                       \
    for (int ks = 0; ks < 4; ++ks)                                                          \
        a_[ks] = *(const bf16x8*)(base_ + aRow + (Q) * 4096 + sl[ks]);                      \
    STAGE_STMT;                                                                             \
    __builtin_amdgcn_s_barrier();                                                           \
    asm volatile("s_waitcnt lgkmcnt(0)" ::: "memory");                                      \
    __builtin_amdgcn_sched_barrier(0);                                                      \
    __builtin_amdgcn_s_setprio(1);                                                          \
    _Pragma("unroll")                                                                       \
    for (int ks = 0; ks < 4; ++ks) {                                                        \
        acc[(Q) * 2 + 0] = __builtin_amdgcn_mfma_f32_32x32x16_bf16(                         \
            a_[ks], b[0][ks], acc[(Q) * 2 + 0], 0, 0, 0);                                   \
        acc[(Q) * 2 + 1] = __builtin_amdgcn_mfma_f32_32x32x16_bf16(                         \
            a_[ks], b[1][ks], acc[(Q) * 2 + 1], 0, 0, 0);                                   \
    }                                                                                       \
    __builtin_amdgcn_s_setprio(0);                                                          \
    VM_STMT;                                                                                \
    __builtin_amdgcn_s_barrier();                                                           \
} while (0)

    // ---- prologue: tile0 complete + tile1 B halves; t1.B may stay in flight ----
    STAGE_HALF(gA0, 0,     0, 0, 0);
    STAGE_HALF(gA0, 0,     1, 0, 0);
    STAGE_HALF(gB0, 32768, 0, 0, 0);
    STAGE_HALF(gB0, 32768, 1, 0, 0);
    STAGE_HALF(gB0, 32768, 0, 1, 1);
    STAGE_HALF(gB0, 32768, 1, 1, 1);
    asm volatile("s_waitcnt vmcnt(4)" ::: "memory");
    __builtin_amdgcn_s_barrier();

    for (int u = 0; u < NITER; ++u) {
        const bool last = (u == NITER - 1);
        const int  t1 = 2 * u + 1, t2 = 2 * u + 2, t3 = 2 * u + 3;

        PHASE(0, 0, 1, { STAGE_HALF(gA0, 0, 0, t1, 1); }, {});
        PHASE(0, 1, 0, { STAGE_HALF(gA0, 0, 1, t1, 1); }, {});
        PHASE(0, 2, 0, { if (!last) STAGE_HALF(gB0, 32768, 0, t2, 0); }, {});
        PHASE(0, 3, 0, { if (!last) STAGE_HALF(gB0, 32768, 1, t2, 0); },
              { if (last) asm volatile("s_waitcnt vmcnt(0)" ::: "memory");
                else      asm volatile("s_waitcnt vmcnt(4)" ::: "memory"); });
        PHASE(1, 0, 1, { if (!last) STAGE_HALF(gA0, 0, 0, t2, 0); }, {});
        PHASE(1, 1, 0, { if (!last) STAGE_HALF(gA0, 0, 1, t2, 0); }, {});
        PHASE(1, 2, 0, { if (!last) STAGE_HALF(gB0, 32768, 0, t3, 1); }, {});
        PHASE(1, 3, 0, { if (!last) STAGE_HALF(gB0, 32768, 1, t3, 1); },
              { if (!last) asm volatile("s_waitcnt vmcnt(4)" ::: "memory"); });
    }
#undef PHASE
#undef STAGE_HALF

    // ---- epilogue: 32x32 D layout: col = lane&31, row = (r&3)+8*(r>>2)+4*(lane>>5) ----
    const int rb = (lane >> 5) * 4;
    float* Cb = C + (size_t)(bm0 + wr * 128) * N_DIM + (bn0 + wc * 64 + l31);
#pragma unroll
    for (int mf = 0; mf < 4; ++mf)
#pragma unroll
        for (int nf = 0; nf < 2; ++nf)
#pragma unroll
            for (int r = 0; r < 16; ++r) {
                const int rr = mf * 32 + (r & 3) + 8 * (r >> 2) + rb;
                Cb[(size_t)rr * N_DIM + nf * 32] = acc[mf * 2 + nf][r];
            }
}

// ---------------------------------------------------------------------------
extern "C" void kernel_launch(void* const* d_in, const int* in_sizes, int n_in,
                              void* d_out, int out_size, void* d_ws, size_t ws_size,
                              hipStream_t stream) {
    const float* x = (const float*)d_in[0];   // (4,2048,2048) fp32
    const float* W = (const float*)d_in[1];   // (4096,2048) fp32
    float* out = (float*)d_out;               // (4,2048,4096) fp32

    unsigned short* xb = (unsigned short*)d_ws;                                      // 32 MB bf16 x
    unsigned short* wt = (unsigned short*)((char*)d_ws + (size_t)M_DIM * K_DIM * 2); // 16 MB WeffT

    build_weff<<<N_DIM, 256, 0, stream>>>(W, wt);
    cvt_x_kernel<<<(M_DIM * K_DIM) / 4 / 256, 256, 0, stream>>>(x, xb);

    dim3 grid((M_DIM / BM) * (N_DIM / BN));   // 512 blocks
    gemm8p<<<grid, 512, 0, stream>>>(xb, wt, out);
}

// Round 5
// 174.750 us; speedup vs baseline: 1.0808x; 1.0808x over previous
//
#include <hip/hip_runtime.h>
#include <hip/hip_bf16.h>
#include <stdint.h>

// out[8192,4096] = x[8192,2048] @ WeffT^T ; WeffT built from W (4096,2048).
#define M_DIM 8192
#define K_DIM 2048
#define N_DIM 4096
#define BM 256
#define BN 256
#define BK 64
#define NT (K_DIM / BK)    // 32 K-tiles
#define NITER (NT / 2)     // 16 iterations, 2 K-tiles each

typedef __attribute__((ext_vector_type(8))) short bf16x8;
typedef __attribute__((ext_vector_type(4))) float f32x4;

__device__ __forceinline__ unsigned short f2bfu(float f) {
    __hip_bfloat16 h = __float2bfloat16(f);
    return __builtin_bit_cast(unsigned short, h);
}

// ---------------------------------------------------------------------------
// Fused prep (one dispatch):
//   blocks [0, N_DIM):            build WeffT row o = blockIdx.x
//   blocks [N_DIM, N_DIM+16384):  x fp32 -> bf16 (float4 -> ushort4)
// Weff row: wo cached in LDS (7 axis-1-shifted terms from LDS); the 6 other
// row streams read as float4 (G13); stores ushort4.
// ---------------------------------------------------------------------------
__global__ __launch_bounds__(256) void prep_fused(const float* __restrict__ x,
                                                  const float* __restrict__ W,
                                                  unsigned short* __restrict__ xb,
                                                  unsigned short* __restrict__ wt) {
    const int bid = blockIdx.x;
    if (bid < N_DIM) {
        __shared__ float row[K_DIM];
        const int o = bid;
        const float* wo = W + (size_t)o * K_DIM;
#pragma unroll
        for (int t = 0; t < 2; ++t)
            ((float4*)row)[threadIdx.x + 256 * t] = ((const float4*)wo)[threadIdx.x + 256 * t];
        __syncthreads();

        const float* rF = W + (size_t)(N_DIM - 1 - o) * K_DIM;
        const float* r1 = W + (size_t)((o - 1) & (N_DIM - 1)) * K_DIM;
        const float* r2 = W + (size_t)((o - 2) & (N_DIM - 1)) * K_DIM;
        const float* r3 = W + (size_t)((o - 3) & (N_DIM - 1)) * K_DIM;
        const float* r4 = W + (size_t)((o - 4) & (N_DIM - 1)) * K_DIM;
        const float* r5 = W + (size_t)((o - 5) & (N_DIM - 1)) * K_DIM;
        unsigned short* w = wt + (size_t)o * K_DIM;

#pragma unroll
        for (int t = 0; t < 2; ++t) {
            const int i0 = (threadIdx.x + 256 * t) * 4;
            const float4 vF = *(const float4*)(rF + i0);
            const float4 v1 = *(const float4*)(r1 + i0);
            const float4 v2 = *(const float4*)(r2 + i0);
            const float4 v3 = *(const float4*)(r3 + i0);
            const float4 v4 = *(const float4*)(r4 + i0);
            const float4 v5 = *(const float4*)(r5 + i0);
            ushort4 ov;
#pragma unroll
            for (int j = 0; j < 4; ++j) {
                const int i = i0 + j;
                float s = row[i] + row[K_DIM - 1 - i]
                        + row[(i - 1) & (K_DIM - 1)] + row[(i - 2) & (K_DIM - 1)]
                        + row[(i - 3) & (K_DIM - 1)] + row[(i - 4) & (K_DIM - 1)]
                        + row[(i - 5) & (K_DIM - 1)];
                s += (&vF.x)[j] + (&v1.x)[j] + (&v2.x)[j]
                   + (&v3.x)[j] + (&v4.x)[j] + (&v5.x)[j];
                (&ov.x)[j] = f2bfu(s);
            }
            *(ushort4*)(w + i0) = ov;
        }
    } else {
        const int idx = (bid - N_DIM) * 256 + threadIdx.x;
        float4 v = ((const float4*)x)[idx];
        ushort4 o;
        o.x = f2bfu(v.x); o.y = f2bfu(v.y); o.z = f2bfu(v.z); o.w = f2bfu(v.w);
        ((ushort4*)xb)[idx] = o;
    }
}

// ---------------------------------------------------------------------------
// GEMM: 256x256 / BK=64 / 8 waves (2Mx4N) / 8-phase schedule (T2+T3+T4+T5).
// EXACT R3 structure (16x16x32 MFMA) — proven 0 bank conflicts, 1070 TF.
//
// LDS per buffer p (64 KiB @ p*65536): A[256][64]bf16 @0 (A0 rows0-127 @0,
// A1 @16384), B @32768 (B0 @32768, B1 @49152). Row=128B=8x16B slots,
// physical slot = logical ^ (row&7), applied on BOTH pre-swizzled global src
// and ds_read addr (rule #21).
//
// Stage schedule: ph1:(2u+1).A0  ph2:(2u+1).A1  ph3:(2u+2).B0  ph4:(2u+2).B1
//                 ph5:(2u+2).A0  ph6:(2u+2).A1  ph7:(2u+3).B0  ph8:(2u+3).B1
// vmcnt(4) at ph4/ph8 only (2 newest half-tiles stay in flight).
// ---------------------------------------------------------------------------
__global__ __launch_bounds__(512, 2) void gemm8p(const unsigned short* __restrict__ Ab,
                                                 const unsigned short* __restrict__ Bt,
                                                 float* __restrict__ C) {
    __shared__ __align__(16) char smem[2 * 65536];

    const int tid  = threadIdx.x;
    const int wave = tid >> 6;
    const int lane = tid & 63;

    // XCD-bijective swizzle (nwg = 512, % 8 == 0)
    const int nwg = gridDim.x;
    const int cpx = nwg >> 3;
    const int wg  = (blockIdx.x & 7) * cpx + (blockIdx.x >> 3);
    const int nbn = N_DIM / BN;                 // 16
    const int bm0 = (wg / nbn) * BM;
    const int bn0 = (wg % nbn) * BN;

    const int wr = wave >> 2;                   // 0..1 (M)
    const int wc = wave & 3;                    // 0..3 (N)

    // ---- staging (pre-swizzled global source) ----
    const int srow = tid >> 3;                          // row within 64-row chunk
    const int lsw  = (lane & 7) ^ ((lane >> 3) & 7);    // logical slot fetched
    const unsigned short* gA0 = Ab + (size_t)(bm0 + srow) * K_DIM + lsw * 8;
    const unsigned short* gB0 = Bt + (size_t)(bn0 + srow) * K_DIM + lsw * 8;

    // ---- ds_read addressing (swizzled; row&7 == lane&7 for all fragment rows) ----
    const int r16  = lane & 15;
    const int x7   = lane & 7;
    const int ksl0 = (((lane >> 4)    ) ^ x7) * 16;     // kk=0 slot
    const int ksl1 = (((lane >> 4) | 4) ^ x7) * 16;     // kk=1 slot
    const int aRow = (wr * 128 + r16) * 128;            // byte offset, A region
    const int bRow = (wc * 64  + r16) * 128 + 32768;    // byte offset, B region

    f32x4  acc[8][4] = {};
    bf16x8 b[4][2];

#define STAGE_HALF(gbase, opoff, h, t, p) do {                                              \
    char* lds_ = smem + (p) * 65536 + (opoff) + (h) * 16384 + wave * 1024;                  \
    const unsigned short* g_ = (gbase) + (size_t)((h) * 128) * K_DIM + (t) * BK;            \
    __builtin_amdgcn_global_load_lds(                                                        \
        (const __attribute__((address_space(1))) unsigned int*)g_,                           \
        (__attribute__((address_space(3))) unsigned int*)lds_, 16, 0, 0);                    \
    __builtin_amdgcn_global_load_lds(                                                        \
        (const __attribute__((address_space(1))) unsigned int*)(g_ + (size_t)64 * K_DIM),    \
        (__attribute__((address_space(3))) unsigned int*)(lds_ + 8192), 16, 0, 0);           \
} while (0)

#define PHASE(P, Q, LOADB, STAGE_STMT, VM_STMT) do {                                        \
    const char* base_ = smem + (P) * 65536;                                                 \
    bf16x8 a_[2][2];                                                                        \
    if (LOADB) {                                                                            \
        _Pragma("unroll")                                                                   \
        for (int fn = 0; fn < 4; ++fn) {                                                    \
            b[fn][0] = *(const bf16x8*)(base_ + bRow + fn * 2048 + ksl0);                   \
            b[fn][1] = *(const bf16x8*)(base_ + bRow + fn * 2048 + ksl1);                   \
        }                                                                                   \
    }                                                                                       \
    a_[0][0] = *(const bf16x8*)(base_ + aRow + (Q) * 4096 + ksl0);                          \
    a_[0][1] = *(const bf16x8*)(base_ + aRow + (Q) * 4096 + ksl1);                          \
    a_[1][0] = *(const bf16x8*)(base_ + aRow + (Q) * 4096 + 2048 + ksl0);                   \
    a_[1][1] = *(const bf16x8*)(base_ + aRow + (Q) * 4096 + 2048 + ksl1);                   \
    STAGE_STMT;                                                                             \
    __builtin_amdgcn_s_barrier();                                                           \
    asm volatile("s_waitcnt lgkmcnt(0)" ::: "memory");                                      \
    __builtin_amdgcn_sched_barrier(0);                                                      \
    __builtin_amdgcn_s_setprio(1);                                                          \
    _Pragma("unroll")                                                                       \
    for (int fm = 0; fm < 2; ++fm)                                                          \
        _Pragma("unroll")                                                                   \
        for (int fn = 0; fn < 4; ++fn) {                                                    \
            acc[(Q)*2 + fm][fn] = __builtin_amdgcn_mfma_f32_16x16x32_bf16(                  \
                a_[fm][0], b[fn][0], acc[(Q)*2 + fm][fn], 0, 0, 0);                         \
            acc[(Q)*2 + fm][fn] = __builtin_amdgcn_mfma_f32_16x16x32_bf16(                  \
                a_[fm][1], b[fn][1], acc[(Q)*2 + fm][fn], 0, 0, 0);                         \
        }                                                                                   \
    __builtin_amdgcn_s_setprio(0);                                                          \
    VM_STMT;                                                                                \
    __builtin_amdgcn_s_barrier();                                                           \
} while (0)

    // ---- prologue: tile0 complete + tile1 B halves; t1.B may stay in flight ----
    STAGE_HALF(gA0, 0,     0, 0, 0);
    STAGE_HALF(gA0, 0,     1, 0, 0);
    STAGE_HALF(gB0, 32768, 0, 0, 0);
    STAGE_HALF(gB0, 32768, 1, 0, 0);
    STAGE_HALF(gB0, 32768, 0, 1, 1);
    STAGE_HALF(gB0, 32768, 1, 1, 1);
    asm volatile("s_waitcnt vmcnt(4)" ::: "memory");
    __builtin_amdgcn_s_barrier();

    for (int u = 0; u < NITER; ++u) {
        const bool last = (u == NITER - 1);
        const int  t1 = 2 * u + 1, t2 = 2 * u + 2, t3 = 2 * u + 3;

        PHASE(0, 0, 1, { STAGE_HALF(gA0, 0, 0, t1, 1); }, {});
        PHASE(0, 1, 0, { STAGE_HALF(gA0, 0, 1, t1, 1); }, {});
        PHASE(0, 2, 0, { if (!last) STAGE_HALF(gB0, 32768, 0, t2, 0); }, {});
        PHASE(0, 3, 0, { if (!last) STAGE_HALF(gB0, 32768, 1, t2, 0); },
              { if (last) asm volatile("s_waitcnt vmcnt(0)" ::: "memory");
                else      asm volatile("s_waitcnt vmcnt(4)" ::: "memory"); });
        PHASE(1, 0, 1, { if (!last) STAGE_HALF(gA0, 0, 0, t2, 0); }, {});
        PHASE(1, 1, 0, { if (!last) STAGE_HALF(gA0, 0, 1, t2, 0); }, {});
        PHASE(1, 2, 0, { if (!last) STAGE_HALF(gB0, 32768, 0, t3, 1); }, {});
        PHASE(1, 3, 0, { if (!last) STAGE_HALF(gB0, 32768, 1, t3, 1); },
              { if (!last) asm volatile("s_waitcnt vmcnt(4)" ::: "memory"); });
    }
#undef PHASE
#undef STAGE_HALF

    // ---- epilogue: D col = lane&15, row = (lane>>4)*4 + r ----
    const int crow = (lane >> 4) * 4;
    const int ccol = lane & 15;
    float* Cb = C + (size_t)(bm0 + wr * 128 + crow) * N_DIM + (bn0 + wc * 64 + ccol);
#pragma unroll
    for (int fm = 0; fm < 8; ++fm)
#pragma unroll
        for (int fn = 0; fn < 4; ++fn)
#pragma unroll
            for (int r = 0; r < 4; ++r)
                Cb[(size_t)(fm * 16 + r) * N_DIM + fn * 16] = acc[fm][fn][r];
}

// ---------------------------------------------------------------------------
extern "C" void kernel_launch(void* const* d_in, const int* in_sizes, int n_in,
                              void* d_out, int out_size, void* d_ws, size_t ws_size,
                              hipStream_t stream) {
    const float* x = (const float*)d_in[0];   // (4,2048,2048) fp32
    const float* W = (const float*)d_in[1];   // (4096,2048) fp32
    float* out = (float*)d_out;               // (4,2048,4096) fp32

    unsigned short* xb = (unsigned short*)d_ws;                                      // 32 MB bf16 x
    unsigned short* wt = (unsigned short*)((char*)d_ws + (size_t)M_DIM * K_DIM * 2); // 16 MB WeffT

    const int cvt_blocks = (M_DIM * K_DIM) / 4 / 256;   // 16384
    prep_fused<<<N_DIM + cvt_blocks, 256, 0, stream>>>(x, W, xb, wt);

    dim3 grid((M_DIM / BM) * (N_DIM / BN));   // 512 blocks
    gemm8p<<<grid, 512, 0, stream>>>(xb, wt, out);
}

// Round 6
// 163.648 us; speedup vs baseline: 1.1542x; 1.0678x over previous
//
#include <hip/hip_runtime.h>
#include <hip/hip_bf16.h>
#include <stdint.h>

// out[8192,4096] = x[8192,2048] @ WeffT^T ; WeffT built from W (4096,2048).
#define M_DIM 8192
#define K_DIM 2048
#define N_DIM 4096
#define BM 256
#define BN 256
#define BK 64
#define NT (K_DIM / BK)    // 32 K-tiles
#define NITER (NT / 2)     // 16 iterations, 2 K-tiles each

typedef __attribute__((ext_vector_type(8))) short bf16x8;
typedef __attribute__((ext_vector_type(4))) float f32x4;

__device__ __forceinline__ unsigned short f2bfu(float f) {
    __hip_bfloat16 h = __float2bfloat16(f);
    return __builtin_bit_cast(unsigned short, h);
}

// ---------------------------------------------------------------------------
// Fused prep (one dispatch):
//   blocks [0, 2048):  build WeffT rows {2b, 2b+1} (paired: o+1's axis-0 roll
//                      streams are o's shifted by one; row0 is o+1's s=1 term)
//   blocks [2048, 2048+16384): x fp32 -> bf16 (float4 -> ushort4)
// ---------------------------------------------------------------------------
__global__ __launch_bounds__(256) void prep_fused(const float* __restrict__ x,
                                                  const float* __restrict__ W,
                                                  unsigned short* __restrict__ xb,
                                                  unsigned short* __restrict__ wt) {
    const int bid = blockIdx.x;
    if (bid < N_DIM / 2) {
        __shared__ float row0[K_DIM];
        __shared__ float row1[K_DIM];
        const int o0 = bid * 2;
        const float* w0 = W + (size_t)o0 * K_DIM;
        const float* w1 = W + (size_t)(o0 + 1) * K_DIM;
#pragma unroll
        for (int t = 0; t < 2; ++t) {
            ((float4*)row0)[threadIdx.x + 256 * t] = ((const float4*)w0)[threadIdx.x + 256 * t];
            ((float4*)row1)[threadIdx.x + 256 * t] = ((const float4*)w1)[threadIdx.x + 256 * t];
        }
        __syncthreads();

        // global streams (7 for the pair)
        const float* rF0 = W + (size_t)(N_DIM - 1 - o0) * K_DIM;
        const float* rF1 = W + (size_t)(N_DIM - 2 - o0) * K_DIM;
        const float* rm1 = W + (size_t)((o0 - 1) & (N_DIM - 1)) * K_DIM;
        const float* rm2 = W + (size_t)((o0 - 2) & (N_DIM - 1)) * K_DIM;
        const float* rm3 = W + (size_t)((o0 - 3) & (N_DIM - 1)) * K_DIM;
        const float* rm4 = W + (size_t)((o0 - 4) & (N_DIM - 1)) * K_DIM;
        const float* rm5 = W + (size_t)((o0 - 5) & (N_DIM - 1)) * K_DIM;
        unsigned short* wo0 = wt + (size_t)o0 * K_DIM;
        unsigned short* wo1 = wo0 + K_DIM;

#pragma unroll
        for (int t = 0; t < 2; ++t) {
            const int i0 = (threadIdx.x + 256 * t) * 4;
            const float4 vF0 = *(const float4*)(rF0 + i0);
            const float4 vF1 = *(const float4*)(rF1 + i0);
            const float4 v1  = *(const float4*)(rm1 + i0);
            const float4 v2  = *(const float4*)(rm2 + i0);
            const float4 v3  = *(const float4*)(rm3 + i0);
            const float4 v4  = *(const float4*)(rm4 + i0);
            const float4 v5  = *(const float4*)(rm5 + i0);
            ushort4 ov0, ov1;
#pragma unroll
            for (int j = 0; j < 4; ++j) {
                const int i = i0 + j;
                // shared axis-0 roll partial (shifts of own row handled per-row)
                float s0 = row0[i] + row0[K_DIM - 1 - i]
                         + row0[(i - 1) & (K_DIM - 1)] + row0[(i - 2) & (K_DIM - 1)]
                         + row0[(i - 3) & (K_DIM - 1)] + row0[(i - 4) & (K_DIM - 1)]
                         + row0[(i - 5) & (K_DIM - 1)];
                s0 += (&vF0.x)[j] + (&v1.x)[j] + (&v2.x)[j]
                    + (&v3.x)[j] + (&v4.x)[j] + (&v5.x)[j];
                (&ov0.x)[j] = f2bfu(s0);

                float s1 = row1[i] + row1[K_DIM - 1 - i]
                         + row1[(i - 1) & (K_DIM - 1)] + row1[(i - 2) & (K_DIM - 1)]
                         + row1[(i - 3) & (K_DIM - 1)] + row1[(i - 4) & (K_DIM - 1)]
                         + row1[(i - 5) & (K_DIM - 1)];
                // axis-1 rolls for o0+1: s=1 -> row0 (LDS), s=2..5 -> rm1..rm4
                s1 += (&vF1.x)[j] + row0[i] + (&v1.x)[j] + (&v2.x)[j]
                    + (&v3.x)[j] + (&v4.x)[j];
                (&ov1.x)[j] = f2bfu(s1);
            }
            *(ushort4*)(wo0 + i0) = ov0;
            *(ushort4*)(wo1 + i0) = ov1;
        }
    } else {
        const int idx = (bid - N_DIM / 2) * 256 + threadIdx.x;
        float4 v = ((const float4*)x)[idx];
        ushort4 o;
        o.x = f2bfu(v.x); o.y = f2bfu(v.y); o.z = f2bfu(v.z); o.w = f2bfu(v.w);
        ((ushort4*)xb)[idx] = o;
    }
}

// ---------------------------------------------------------------------------
// GEMM: 256x256 / BK=64 / 8 waves (2Mx4N) / 8-phase schedule (T2+T3+T4+T5),
// R6: 3-half-tile-deep prefetch, vmcnt(6) at ph4/ph8 (m201 steady state).
//
// LDS per buffer p (64 KiB @ p*65536): A @0 (A0 rows0-127 @0, A1 @16384),
// B @32768 (B0 @32768, B1 @49152). Row=128B=8x16B slots, physical slot =
// logical ^ (row&7), both-sides swizzle (rule #21).
//
// Reads: tile in buf0 at ph1-4 (B@ph1; A0@ph1-2; A1@ph3-4), buf1 at ph5-8.
// Stage ledger (steady state; slot free-after / landing forced-by verified):
//   ph1: t1.A1->buf1   (slot free after prev ph8; forced by ph4 vmcnt(6))
//   ph2: t2.B0->buf0   (free after ph1; forced by next ph8... by ph8 vmcnt)
//   ph3: t2.B1->buf0   (free after ph1; forced by ph8 vmcnt(6))
//   ph4: t2.A0->buf0, vmcnt(6)   [forces ph1 and older; allows ph2-4]
//   ph5: t2.A1->buf0   (free after ph4)
//   ph6: t3.B0->buf1   (free after ph5)
//   ph7: t3.B1->buf1   (free after ph5)
//   ph8: t3.A0->buf1, vmcnt(6)   [forces ph5 and older; allows ph6-8]
// Prologue: t0.{B0,B1,A0,A1}, t1.{B0,B1,A0} then vmcnt(6) (t0 fully landed).
// Last iteration: t2/t3 stages guarded out; ph4 uses vmcnt(0).
// ---------------------------------------------------------------------------
__global__ __launch_bounds__(512, 2) void gemm8p(const unsigned short* __restrict__ Ab,
                                                 const unsigned short* __restrict__ Bt,
                                                 float* __restrict__ C) {
    __shared__ __align__(16) char smem[2 * 65536];

    const int tid  = threadIdx.x;
    const int wave = tid >> 6;
    const int lane = tid & 63;

    // XCD-bijective swizzle (nwg = 512, % 8 == 0)
    const int nwg = gridDim.x;
    const int cpx = nwg >> 3;
    const int wg  = (blockIdx.x & 7) * cpx + (blockIdx.x >> 3);
    const int nbn = N_DIM / BN;                 // 16
    const int bm0 = (wg / nbn) * BM;
    const int bn0 = (wg % nbn) * BN;

    const int wr = wave >> 2;                   // 0..1 (M)
    const int wc = wave & 3;                    // 0..3 (N)

    // ---- staging (pre-swizzled global source) ----
    const int srow = tid >> 3;                          // row within 64-row chunk
    const int lsw  = (lane & 7) ^ ((lane >> 3) & 7);    // logical slot fetched
    const unsigned short* gA0 = Ab + (size_t)(bm0 + srow) * K_DIM + lsw * 8;
    const unsigned short* gB0 = Bt + (size_t)(bn0 + srow) * K_DIM + lsw * 8;

    // ---- ds_read addressing (swizzled; conflict-free, proven R3/R5) ----
    const int r16  = lane & 15;
    const int x7   = lane & 7;
    const int ksl0 = (((lane >> 4)    ) ^ x7) * 16;     // kk=0 slot
    const int ksl1 = (((lane >> 4) | 4) ^ x7) * 16;     // kk=1 slot
    const int aRow = (wr * 128 + r16) * 128;            // byte offset, A region
    const int bRow = (wc * 64  + r16) * 128 + 32768;    // byte offset, B region

    f32x4  acc[8][4] = {};
    bf16x8 b[4][2];

#define STAGE_HALF(gbase, opoff, h, t, p) do {                                              \
    char* lds_ = smem + (p) * 65536 + (opoff) + (h) * 16384 + wave * 1024;                  \
    const unsigned short* g_ = (gbase) + (size_t)((h) * 128) * K_DIM + (t) * BK;            \
    __builtin_amdgcn_global_load_lds(                                                        \
        (const __attribute__((address_space(1))) unsigned int*)g_,                           \
        (__attribute__((address_space(3))) unsigned int*)lds_, 16, 0, 0);                    \
    __builtin_amdgcn_global_load_lds(                                                        \
        (const __attribute__((address_space(1))) unsigned int*)(g_ + (size_t)64 * K_DIM),    \
        (__attribute__((address_space(3))) unsigned int*)(lds_ + 8192), 16, 0, 0);           \
} while (0)

#define PHASE(P, Q, LOADB, STAGE_STMT, VM_STMT) do {                                        \
    const char* base_ = smem + (P) * 65536;                                                 \
    bf16x8 a_[2][2];                                                                        \
    if (LOADB) {                                                                            \
        _Pragma("unroll")                                                                   \
        for (int fn = 0; fn < 4; ++fn) {                                                    \
            b[fn][0] = *(const bf16x8*)(base_ + bRow + fn * 2048 + ksl0);                   \
            b[fn][1] = *(const bf16x8*)(base_ + bRow + fn * 2048 + ksl1);                   \
        }                                                                                   \
    }                                                                                       \
    a_[0][0] = *(const bf16x8*)(base_ + aRow + (Q) * 4096 + ksl0);                          \
    a_[0][1] = *(const bf16x8*)(base_ + aRow + (Q) * 4096 + ksl1);                          \
    a_[1][0] = *(const bf16x8*)(base_ + aRow + (Q) * 4096 + 2048 + ksl0);                   \
    a_[1][1] = *(const bf16x8*)(base_ + aRow + (Q) * 4096 + 2048 + ksl1);                   \
    STAGE_STMT;                                                                             \
    __builtin_amdgcn_s_barrier();                                                           \
    asm volatile("s_waitcnt lgkmcnt(0)" ::: "memory");                                      \
    __builtin_amdgcn_sched_barrier(0);                                                      \
    __builtin_amdgcn_s_setprio(1);                                                          \
    _Pragma("unroll")                                                                       \
    for (int fm = 0; fm < 2; ++fm)                                                          \
        _Pragma("unroll")                                                                   \
        for (int fn = 0; fn < 4; ++fn) {                                                    \
            acc[(Q)*2 + fm][fn] = __builtin_amdgcn_mfma_f32_16x16x32_bf16(                  \
                a_[fm][0], b[fn][0], acc[(Q)*2 + fm][fn], 0, 0, 0);                         \
            acc[(Q)*2 + fm][fn] = __builtin_amdgcn_mfma_f32_16x16x32_bf16(                  \
                a_[fm][1], b[fn][1], acc[(Q)*2 + fm][fn], 0, 0, 0);                         \
        }                                                                                   \
    __builtin_amdgcn_s_setprio(0);                                                          \
    VM_STMT;                                                                                \
    __builtin_amdgcn_s_barrier();                                                           \
} while (0)

    // ---- prologue: t0 complete + t1.{B0,B1,A0}; newest 3 halves may fly ----
    STAGE_HALF(gB0, 32768, 0, 0, 0);
    STAGE_HALF(gB0, 32768, 1, 0, 0);
    STAGE_HALF(gA0, 0,     0, 0, 0);
    STAGE_HALF(gA0, 0,     1, 0, 0);
    STAGE_HALF(gB0, 32768, 0, 1, 1);
    STAGE_HALF(gB0, 32768, 1, 1, 1);
    STAGE_HALF(gA0, 0,     0, 1, 1);
    asm volatile("s_waitcnt vmcnt(6)" ::: "memory");
    __builtin_amdgcn_s_barrier();

    for (int u = 0; u < NITER; ++u) {
        const bool last = (u == NITER - 1);
        const int  t1 = 2 * u + 1, t2 = 2 * u + 2, t3 = 2 * u + 3;

        PHASE(0, 0, 1, { STAGE_HALF(gA0, 0, 1, t1, 1); }, {});                 // t1.A1
        PHASE(0, 1, 0, { if (!last) STAGE_HALF(gB0, 32768, 0, t2, 0); }, {});  // t2.B0
        PHASE(0, 2, 0, { if (!last) STAGE_HALF(gB0, 32768, 1, t2, 0); }, {});  // t2.B1
        PHASE(0, 3, 0, { if (!last) STAGE_HALF(gA0, 0, 0, t2, 0); },           // t2.A0
              { if (last) asm volatile("s_waitcnt vmcnt(0)" ::: "memory");
                else      asm volatile("s_waitcnt vmcnt(6)" ::: "memory"); });
        PHASE(1, 0, 1, { if (!last) STAGE_HALF(gA0, 0, 1, t2, 0); }, {});      // t2.A1
        PHASE(1, 1, 0, { if (!last) STAGE_HALF(gB0, 32768, 0, t3, 1); }, {});  // t3.B0
        PHASE(1, 2, 0, { if (!last) STAGE_HALF(gB0, 32768, 1, t3, 1); }, {});  // t3.B1
        PHASE(1, 3, 0, { if (!last) STAGE_HALF(gA0, 0, 0, t3, 1); },           // t3.A0
              { if (!last) asm volatile("s_waitcnt vmcnt(6)" ::: "memory"); });
    }
#undef PHASE
#undef STAGE_HALF

    // ---- epilogue: D col = lane&15, row = (lane>>4)*4 + r ----
    const int crow = (lane >> 4) * 4;
    const int ccol = lane & 15;
    float* Cb = C + (size_t)(bm0 + wr * 128 + crow) * N_DIM + (bn0 + wc * 64 + ccol);
#pragma unroll
    for (int fm = 0; fm < 8; ++fm)
#pragma unroll
        for (int fn = 0; fn < 4; ++fn)
#pragma unroll
            for (int r = 0; r < 4; ++r)
                Cb[(size_t)(fm * 16 + r) * N_DIM + fn * 16] = acc[fm][fn][r];
}

// ---------------------------------------------------------------------------
extern "C" void kernel_launch(void* const* d_in, const int* in_sizes, int n_in,
                              void* d_out, int out_size, void* d_ws, size_t ws_size,
                              hipStream_t stream) {
    const float* x = (const float*)d_in[0];   // (4,2048,2048) fp32
    const float* W = (const float*)d_in[1];   // (4096,2048) fp32
    float* out = (float*)d_out;               // (4,2048,4096) fp32

    unsigned short* xb = (unsigned short*)d_ws;                                      // 32 MB bf16 x
    unsigned short* wt = (unsigned short*)((char*)d_ws + (size_t)M_DIM * K_DIM * 2); // 16 MB WeffT

    const int cvt_blocks = (M_DIM * K_DIM) / 4 / 256;   // 16384
    prep_fused<<<N_DIM / 2 + cvt_blocks, 256, 0, stream>>>(x, W, xb, wt);

    dim3 grid((M_DIM / BM) * (N_DIM / BN));   // 512 blocks
    gemm8p<<<grid, 512, 0, stream>>>(xb, wt, out);
}